// Round 2
// baseline (52.830 us; speedup 1.0000x reference)
//
#include <hip/hip_runtime.h>
#include <stdint.h>

#define IN_F   8192
#define OUT_F  8192
#define M_TOK  32
#define BN     32      // output channels per block
#define BK     128     // K elements staged per iteration
#define NIT    (IN_F / BK)   // 64
#define PF     2       // prefetch depth (divides NIT); covers ~900cy HBM latency at floor pace
#define LDSS   136     // LDS row stride in bf16 elems (272B -> 2-way bank alias = free, m136)

typedef float  f32x4  __attribute__((ext_vector_type(4)));
typedef short  short8 __attribute__((ext_vector_type(8)));

// pack two fp32 into two bf16 (truncation; exact for int8-valued floats)
__device__ inline unsigned pk_bf16(float f0, float f1) {
    unsigned u0 = __builtin_bit_cast(unsigned, f0);
    unsigned u1 = __builtin_bit_cast(unsigned, f1);
    return (u0 >> 16) | (u1 & 0xFFFF0000u);
}

__global__ __launch_bounds__(256) void qlin_mfma(
    const float* __restrict__ x, const int* __restrict__ wq,
    const float* __restrict__ scale, float* __restrict__ out) {

    __shared__ ushort ldsA[2][M_TOK][LDSS];  // x tile, bf16
    __shared__ ushort ldsW[2][BN][LDSS];     // weight tile, bf16

    const int t  = threadIdx.x;
    const int o0 = blockIdx.x * BN;

    // staging: 256 threads -> 32 rows x 8 col-chunks of 16 elements
    const int r  = t >> 3;          // row 0..31
    const int cc = (t & 7) * 16;    // element col base 0..112

    const float* xp = x  + (size_t)r * IN_F + cc;
    const int*   wp = wq + (size_t)(o0 + r) * IN_F + cc;   // weights are INT32 (sign-extended int8)

    float4 abuf[PF][4];   // 16 fp32 / thread / iter
    int4   wbuf[PF][4];   // 16 int32 / thread / iter

    #pragma unroll
    for (int p = 0; p < PF; ++p) {
        #pragma unroll
        for (int q = 0; q < 4; ++q) {
            abuf[p][q] = *reinterpret_cast<const float4*>(xp + p * BK + 4 * q);
            wbuf[p][q] = *reinterpret_cast<const int4*>(wp + p * BK + 4 * q);
        }
    }

    // compute decomposition: 4 waves, one 16x16 output tile each
    const int wid  = t >> 6;
    const int lane = t & 63;
    const int mt   = wid & 1;          // token half
    const int nt   = wid >> 1;         // channel half
    const int frow = lane & 15;
    const int fk   = (lane >> 4) * 8;

    f32x4 acc = {0.f, 0.f, 0.f, 0.f};

    for (int base = 0; base < NIT; base += PF) {
        #pragma unroll
        for (int p = 0; p < PF; ++p) {
            const int it  = base + p;
            const int buf = it & 1;

            // ---- stage x (fp32 -> bf16) ----
            {
                float4 v0 = abuf[p][0], v1 = abuf[p][1];
                float4 v2 = abuf[p][2], v3 = abuf[p][3];
                uint4 w0, w1;
                w0.x = pk_bf16(v0.x, v0.y); w0.y = pk_bf16(v0.z, v0.w);
                w0.z = pk_bf16(v1.x, v1.y); w0.w = pk_bf16(v1.z, v1.w);
                w1.x = pk_bf16(v2.x, v2.y); w1.y = pk_bf16(v2.z, v2.w);
                w1.z = pk_bf16(v3.x, v3.y); w1.w = pk_bf16(v3.z, v3.w);
                *reinterpret_cast<uint4*>(&ldsA[buf][r][cc])     = w0;
                *reinterpret_cast<uint4*>(&ldsA[buf][r][cc + 8]) = w1;
            }
            // ---- stage W (int32 -> bf16; exact, |v| <= 128) ----
            {
                int4 a0 = wbuf[p][0], a1 = wbuf[p][1];
                int4 a2 = wbuf[p][2], a3 = wbuf[p][3];
                uint4 w0, w1;
                w0.x = pk_bf16((float)a0.x, (float)a0.y);
                w0.y = pk_bf16((float)a0.z, (float)a0.w);
                w0.z = pk_bf16((float)a1.x, (float)a1.y);
                w0.w = pk_bf16((float)a1.z, (float)a1.w);
                w1.x = pk_bf16((float)a2.x, (float)a2.y);
                w1.y = pk_bf16((float)a2.z, (float)a2.w);
                w1.z = pk_bf16((float)a3.x, (float)a3.y);
                w1.w = pk_bf16((float)a3.z, (float)a3.w);
                *reinterpret_cast<uint4*>(&ldsW[buf][r][cc])     = w0;
                *reinterpret_cast<uint4*>(&ldsW[buf][r][cc + 8]) = w1;
            }

            // ---- issue loads PF iterations ahead ----
            const int nit = it + PF;
            if (nit < NIT) {
                #pragma unroll
                for (int q = 0; q < 4; ++q) {
                    abuf[p][q] = *reinterpret_cast<const float4*>(xp + nit * BK + 4 * q);
                    wbuf[p][q] = *reinterpret_cast<const int4*>(wp + nit * BK + 4 * q);
                }
            }

            __syncthreads();

            // ---- compute: 4 K-substeps of 32 ----
            const ushort* aB = &ldsA[buf][mt * 16 + frow][fk];
            const ushort* wB = &ldsW[buf][nt * 16 + frow][fk];
            #pragma unroll
            for (int ks = 0; ks < 4; ++ks) {
                short8 af = *reinterpret_cast<const short8*>(aB + ks * 32);
                short8 bf = *reinterpret_cast<const short8*>(wB + ks * 32);
                acc = __builtin_amdgcn_mfma_f32_16x16x32_bf16(af, bf, acc, 0, 0, 0);
            }
            // single barrier per iter is sufficient: same-buffer reuse is
            // separated by the NEXT iteration's barrier (2-deep LDS).
        }
    }

    // ---- epilogue: per-channel scale, store ----
    // C/D layout (m89-verified): col = lane&15, row = (lane>>4)*4 + reg
    const int ocol = o0 + nt * 16 + frow;
    const float s  = scale[ocol];
    const int  m0  = mt * 16 + (lane >> 4) * 4;
    #pragma unroll
    for (int rg = 0; rg < 4; ++rg)
        out[(size_t)(m0 + rg) * OUT_F + ocol] = acc[rg] * s;
}

extern "C" void kernel_launch(void* const* d_in, const int* in_sizes, int n_in,
                              void* d_out, int out_size, void* d_ws, size_t ws_size,
                              hipStream_t stream) {
    const float* x  = (const float*)d_in[0];
    const int*   wq = (const int*)d_in[1];     // integer inputs arrive as int32
    const float* sc = (const float*)d_in[2];
    float* out = (float*)d_out;

    qlin_mfma<<<OUT_F / BN, 256, 0, stream>>>(x, wq, sc, out);
}